// Round 2
// baseline (625.882 us; speedup 1.0000x reference)
//
#include <hip/hip_runtime.h>
#include <hip/hip_bf16.h>
#include <math.h>
#include <stddef.h>

#define DEV __device__ __forceinline__
__device__ const float BNS = 0.99999500003749968f; // 1/sqrt(1+1e-5)

// Problem geometry: B=2, M=256 -> NG=512 groups, N=64 points, KNN=16
// CIN=64 (3 xyz + 61 feats), edge1 O=64, edge2 O=128, SUMM=192,
// CALIB=64, EXP=256/512, OUT=256.  All inputs/outputs are FLOAT32.

// ---------------- kernel A: knn + build x0 (64ch x 64pts, f32) --------------
__global__ __launch_bounds__(64) void k_knn(const float* __restrict__ xyz,
    const float* __restrict__ feats, int* __restrict__ idxo, float* __restrict__ x0){
  int bm = blockIdx.x; int n = threadIdx.x;
  __shared__ float sx0[64], sx1[64], sx2[64], sxx[64];
  __shared__ float pd[64][65];
  const float* xp = xyz + (size_t)(bm*64+n)*3;
  float px=xp[0], py=xp[1], pz=xp[2];
  sx0[n]=px; sx1[n]=py; sx2[n]=pz; sxx[n]=px*px+py*py+pz*pz;
  __syncthreads();
  float xxn = sxx[n];
  for(int m=0;m<64;m++){
    float inner = px*sx0[m]+py*sx1[m]+pz*sx2[m];
    pd[n][m] = 2.0f*inner - xxn - sxx[m];
  }
  int* ip = idxo + bm*1024 + n*16;
  for(int j=0;j<16;j++){
    float best=-3.4e38f; int bi=0;
    for(int m=0;m<64;m++){ float v=pd[n][m]; if(v>best){best=v;bi=m;} }
    ip[j]=bi; pd[n][bi]=-3.4e38f;  // strict > keeps lowest index on ties (matches lax.top_k)
  }
  float* xb = x0 + (size_t)bm*4096;
  xb[0*64+n]=px; xb[1*64+n]=py; xb[2*64+n]=pz;
  const float* fp = feats + (size_t)(bm*64+n)*61;
  for(int c=0;c<61;c++) xb[(3+c)*64+n]=fp[c];
}

// ---------------- edgeconv: y = relu(bn(W1@nb + (W2-W1)@ctr)), max over k ---
// z[o][m] = sum_c W1[o][c] x[c][m]; dd[o][n] = sum_c (W2-W1)[o][c] x[c][n]
// out[o][n] = max(0, max_k ( s*(z[o][idx[n][k]] + dd[o][n]) + b ))
template<int O>
__global__ __launch_bounds__(256) void k_edge(const float* __restrict__ xin_g, int ld_in,
   const int* __restrict__ idxg, const float* __restrict__ W, const float* __restrict__ gg,
   const float* __restrict__ bb, float* __restrict__ outg, int ld_out){
  __shared__ float xin[4096];
  __shared__ float zs[4096];
  __shared__ float dds[4096];
  int bm=blockIdx.x, tid=threadIdx.x;
  for(int i=tid;i<4096;i+=256) xin[i]=xin_g[(size_t)bm*ld_in+i];
  const int* ip0 = idxg + bm*1024;
  for(int oc=0; oc<O; oc+=64){
    __syncthreads();
    for(int i=tid;i<4096;i+=256){
      int o=oc+(i>>6), m=i&63;
      float az=0.f, ad=0.f;
      #pragma unroll 8
      for(int c=0;c<64;c++){
        float w1v=W[o*128+c];
        float w2v=W[o*128+64+c];
        float xv=xin[c*64+m];
        az += w1v*xv; ad += (w2v-w1v)*xv;
      }
      zs[i]=az; dds[i]=ad;
    }
    __syncthreads();
    for(int i=tid;i<4096;i+=256){
      int o=oc+(i>>6), n=i&63;
      float s=gg[o]*BNS, bi=bb[o];
      float base=dds[i];
      const int* ip=ip0+n*16;
      int zrow=(i>>6)<<6;
      float v=0.f;  // relu(max) == max(0, max_k pre-relu)
      #pragma unroll
      for(int k=0;k<16;k++){ int mi=ip[k]; v=fmaxf(v, s*(zs[zrow+mi]+base)+bi); }
      outg[(size_t)bm*ld_out + o*64+n]=v;
    }
  }
}

// ---------------- cal1: 192->64, bn+relu ------------------------------------
__global__ __launch_bounds__(256) void k_cal1(const float* __restrict__ cat,
    const float* __restrict__ W, const float* __restrict__ g, const float* __restrict__ b,
    float* __restrict__ c1){
  __shared__ float xs[12288];
  int bm=blockIdx.x, tid=threadIdx.x;
  for(int i=tid;i<12288;i+=256) xs[i]=cat[(size_t)bm*12288+i];
  __syncthreads();
  int ot=(tid>>4)*4, nt=(tid&15)*4;
  float acc[4][4];
  #pragma unroll
  for(int a=0;a<4;a++) for(int d=0;d<4;d++) acc[a][d]=0.f;
  for(int c=0;c<192;c++){
    float wv[4]; float xv[4];
    #pragma unroll
    for(int a=0;a<4;a++) wv[a]=W[(ot+a)*192+c];
    #pragma unroll
    for(int d=0;d<4;d++) xv[d]=xs[c*64+nt+d];
    #pragma unroll
    for(int a=0;a<4;a++)
      #pragma unroll
      for(int d=0;d<4;d++) acc[a][d]+=wv[a]*xv[d];
  }
  float* outp=c1+(size_t)bm*4096;
  #pragma unroll
  for(int a=0;a<4;a++){ float s=g[ot+a]*BNS, bi=b[ot+a];
    #pragma unroll
    for(int d=0;d<4;d++) outp[(ot+a)*64+nt+d]=fmaxf(acc[a][d]*s+bi,0.f); }
}

// ---------------- cal2 + sigmoid gate (in place on cat) ---------------------
__global__ __launch_bounds__(256) void k_cal2(const float* __restrict__ c1,
    const float* __restrict__ W, const float* __restrict__ bias, float* __restrict__ cat){
  __shared__ float xs[4096];
  int bm=blockIdx.x, tid=threadIdx.x;
  for(int i=tid;i<4096;i+=256) xs[i]=c1[(size_t)bm*4096+i];
  __syncthreads();
  float* cp=cat+(size_t)bm*12288;
  for(int t=tid;t<768;t+=256){
    int ot=(t>>4)*4, nt=(t&15)*4;
    float acc[4][4];
    #pragma unroll
    for(int a=0;a<4;a++) for(int d=0;d<4;d++) acc[a][d]=0.f;
    for(int c=0;c<64;c++){
      float wv[4]; float xv[4];
      #pragma unroll
      for(int a=0;a<4;a++) wv[a]=W[(ot+a)*64+c];
      #pragma unroll
      for(int d=0;d<4;d++) xv[d]=xs[c*64+nt+d];
      #pragma unroll
      for(int a=0;a<4;a++)
        #pragma unroll
        for(int d=0;d<4;d++) acc[a][d]+=wv[a]*xv[d];
    }
    #pragma unroll
    for(int a=0;a<4;a++){ float bv=bias[ot+a];
      #pragma unroll
      for(int d=0;d<4;d++){
        float v=acc[a][d]+bv;
        float sg=1.f/(1.f+expf(-v));
        cp[(ot+a)*64+nt+d]*=sg;
      } }
  }
}

// ---------------- exp1: 192->256, bn+relu -----------------------------------
__global__ __launch_bounds__(256) void k_exp1(const float* __restrict__ cat,
    const float* __restrict__ W, const float* __restrict__ g, const float* __restrict__ b,
    float* __restrict__ p1){
  __shared__ float xs[12288];
  int bm=blockIdx.x, tid=threadIdx.x;
  for(int i=tid;i<12288;i+=256) xs[i]=cat[(size_t)bm*12288+i];
  __syncthreads();
  int ot=(tid>>3)*8, nt=(tid&7)*8;
  float acc[8][8];
  #pragma unroll
  for(int a=0;a<8;a++) for(int d=0;d<8;d++) acc[a][d]=0.f;
  for(int c=0;c<192;c++){
    float wv[8]; float xv[8];
    #pragma unroll
    for(int a=0;a<8;a++) wv[a]=W[(ot+a)*192+c];
    #pragma unroll
    for(int d=0;d<8;d++) xv[d]=xs[c*64+nt+d];
    #pragma unroll
    for(int a=0;a<8;a++)
      #pragma unroll
      for(int d=0;d<8;d++) acc[a][d]+=wv[a]*xv[d];
  }
  float* op=p1+(size_t)bm*16384;
  #pragma unroll
  for(int a=0;a<8;a++){ float s=g[ot+a]*BNS, bi=b[ot+a];
    #pragma unroll
    for(int d=0;d<8;d++) op[(ot+a)*64+nt+d]=fmaxf(acc[a][d]*s+bi,0.f); }
}

// ---------------- exp2: 256->512, bn+relu, max over n, write (b,512,m) ------
__global__ __launch_bounds__(256) void k_exp2(const float* __restrict__ p1,
    const float* __restrict__ W, const float* __restrict__ gg, const float* __restrict__ bb,
    float* __restrict__ pool){
  __shared__ float xs[16384]; // exactly 64KB
  int bm=blockIdx.x, tid=threadIdx.x;
  for(int i=tid;i<16384;i+=256) xs[i]=p1[(size_t)bm*16384+i];
  __syncthreads();
  int oti=tid>>2;   // 64 o-tiles of 8
  int ng=tid&3;     // 4 n-groups of 16
  int ob=oti*8;
  float s[8],bi[8],omax[8];
  #pragma unroll
  for(int a=0;a<8;a++){ s[a]=gg[ob+a]*BNS; bi[a]=bb[ob+a]; omax[a]=0.f; }
  #pragma unroll
  for(int half=0;half<2;half++){
    int nt=ng*16+half*8;
    float acc[8][8];
    #pragma unroll
    for(int a=0;a<8;a++) for(int d=0;d<8;d++) acc[a][d]=0.f;
    for(int c=0;c<256;c++){
      float wv[8]; float xv[8];
      #pragma unroll
      for(int a=0;a<8;a++) wv[a]=W[(ob+a)*256+c];
      #pragma unroll
      for(int d=0;d<8;d++) xv[d]=xs[c*64+nt+d];
      #pragma unroll
      for(int a=0;a<8;a++)
        #pragma unroll
        for(int d=0;d<8;d++) acc[a][d]+=wv[a]*xv[d];
    }
    #pragma unroll
    for(int a=0;a<8;a++)
      #pragma unroll
      for(int d=0;d<8;d++) omax[a]=fmaxf(omax[a], acc[a][d]*s[a]+bi[a]);
  }
  // lanes oti*4+ng adjacent -> shuffle max over ng
  #pragma unroll
  for(int a=0;a<8;a++){
    float v=omax[a];
    v=fmaxf(v, __shfl_xor(v,1));
    v=fmaxf(v, __shfl_xor(v,2));
    omax[a]=v;
  }
  if(ng==0){
    int b=bm>>8, m=bm&255;
    #pragma unroll
    for(int a=0;a<8;a++) pool[((size_t)b*512+ob+a)*256+m]=omax[a];
  }
}

// ---------------- red: 512->256 bn relu, then bn(x+x,g1,b1) -----------------
__global__ __launch_bounds__(256) void k_red(const float* __restrict__ pool,
   const float* __restrict__ W, const float* __restrict__ g, const float* __restrict__ b,
   const float* __restrict__ g1, const float* __restrict__ b1, float* __restrict__ x1){
  int e=blockIdx.x*256+threadIdx.x;
  int bb=e>>16, o=(e>>8)&255, m=e&255;
  const float* pp=pool+(size_t)bb*131072+m;
  const float* wr=W+o*512;
  float acc=0.f;
  #pragma unroll 4
  for(int c=0;c<512;c++) acc+=wr[c]*pp[(size_t)c*256];
  float r=fmaxf(acc*g[o]*BNS+b[o],0.f);
  x1[e]=2.f*r*(g1[o]*BNS)+b1[o];
}

// ---------------- sc1: h = relu(W@x1 + b) -----------------------------------
__global__ __launch_bounds__(256) void k_sc1(const float* __restrict__ x1,
   const float* __restrict__ W, const float* __restrict__ b, float* __restrict__ h){
  int e=blockIdx.x*256+threadIdx.x;
  int bb=e>>16, o=(e>>8)&255, m=e&255;
  const float* xp=x1+(size_t)bb*65536+m;
  const float* wr=W+o*256;
  float acc=0.f;
  #pragma unroll 4
  for(int c=0;c<256;c++) acc+=wr[c]*xp[(size_t)c*256];
  h[e]=fmaxf(acc+b[o],0.f);
}

// ---------------- sc2 + residual + bn2 -> f32 out ---------------------------
__global__ __launch_bounds__(256) void k_sc2(const float* __restrict__ h,
   const float* __restrict__ x1, const float* __restrict__ W, const float* __restrict__ b,
   const float* __restrict__ g2, const float* __restrict__ b2, float* __restrict__ out){
  int e=blockIdx.x*256+threadIdx.x;
  int bb=e>>16, o=(e>>8)&255, m=e&255;
  const float* hp=h+(size_t)bb*65536+m;
  const float* wr=W+o*256;
  float acc=0.f;
  #pragma unroll 4
  for(int c=0;c<256;c++) acc+=wr[c]*hp[(size_t)c*256];
  float v=x1[e]+acc+b[o];
  out[e]=v*(g2[o]*BNS)+b2[o];
}

extern "C" void kernel_launch(void* const* d_in, const int* in_sizes, int n_in,
                              void* d_out, int out_size, void* d_ws, size_t ws_size,
                              hipStream_t stream){
  const float* xyz     =(const float*)d_in[0];
  const float* feats   =(const float*)d_in[1];
  const float* e1_w    =(const float*)d_in[2];
  const float* e1_g    =(const float*)d_in[3];
  const float* e1_b    =(const float*)d_in[4];
  const float* e2_w    =(const float*)d_in[5];
  const float* e2_g    =(const float*)d_in[6];
  const float* e2_b    =(const float*)d_in[7];
  const float* cal1_w  =(const float*)d_in[8];
  const float* cal1_g  =(const float*)d_in[9];
  const float* cal1_b  =(const float*)d_in[10];
  const float* cal2_w  =(const float*)d_in[11];
  const float* cal2_bias=(const float*)d_in[12];
  const float* exp1_w  =(const float*)d_in[13];
  const float* exp1_g  =(const float*)d_in[14];
  const float* exp1_b  =(const float*)d_in[15];
  const float* exp2_w  =(const float*)d_in[16];
  const float* exp2_g  =(const float*)d_in[17];
  const float* exp2_b  =(const float*)d_in[18];
  const float* red_w   =(const float*)d_in[19];
  const float* red_g   =(const float*)d_in[20];
  const float* red_b   =(const float*)d_in[21];
  const float* sc1_w   =(const float*)d_in[22];
  const float* sc1_b   =(const float*)d_in[23];
  const float* sc2_w   =(const float*)d_in[24];
  const float* sc2_b   =(const float*)d_in[25];
  const float* sc_n1_g =(const float*)d_in[26];
  const float* sc_n1_b =(const float*)d_in[27];
  const float* sc_n2_g =(const float*)d_in[28];
  const float* sc_n2_b =(const float*)d_in[29];

  char* wsb=(char*)d_ws;
  // workspace layout (bytes):
  int*   idx =(int*)  (wsb + 0);          // 512*1024*4          = 2 MB
  float* x0  =(float*)(wsb + 2097152);    // 512*4096*4          = 8 MB (reused as c1)
  float* cat =(float*)(wsb + 10485760);   // 512*12288*4         = 24 MB (a1 rows 0-63, a2 rows 64-191; gated in place)
  float* p1  =(float*)(wsb + 35651584);   // 512*16384*4         = 32 MB
  float* pool=(float*)(wsb + 69206016);   // 2*512*256*4         = 1 MB
  float* x1  =(float*)(wsb + 70254592);   // 2*256*256*4
  float* hbuf=(float*)(wsb + 70778880);   // 2*256*256*4
  float* c1  = x0; // x0 dead after edge2

  k_knn      <<<512, 64,0,stream>>>(xyz,feats,idx,x0);
  k_edge< 64><<<512,256,0,stream>>>(x0,   4096,idx,e1_w,e1_g,e1_b,cat,     12288);
  k_edge<128><<<512,256,0,stream>>>(cat, 12288,idx,e2_w,e2_g,e2_b,cat+4096,12288);
  k_cal1     <<<512,256,0,stream>>>(cat,cal1_w,cal1_g,cal1_b,c1);
  k_cal2     <<<512,256,0,stream>>>(c1,cal2_w,cal2_bias,cat);
  k_exp1     <<<512,256,0,stream>>>(cat,exp1_w,exp1_g,exp1_b,p1);
  k_exp2     <<<512,256,0,stream>>>(p1,exp2_w,exp2_g,exp2_b,pool);
  k_red      <<<512,256,0,stream>>>(pool,red_w,red_g,red_b,sc_n1_g,sc_n1_b,x1);
  k_sc1      <<<512,256,0,stream>>>(x1,sc1_w,sc1_b,hbuf);
  k_sc2      <<<512,256,0,stream>>>(hbuf,x1,sc2_w,sc2_b,sc_n2_g,sc_n2_b,(float*)d_out);
}

// Round 3
// 494.540 us; speedup vs baseline: 1.2656x; 1.2656x over previous
//
#include <hip/hip_runtime.h>
#include <hip/hip_bf16.h>
#include <math.h>
#include <stddef.h>

#define DEV __device__ __forceinline__
__device__ const float BNS = 0.99999500003749968f; // 1/sqrt(1+1e-5)

// Problem geometry: B=2, M=256 -> 512 bm groups, N=64 points, KNN=16
// CIN=64, edge1 O=64, edge2 O=128, SUMM=192, CALIB=64, EXP=256/512, OUT=256.
// All inputs/outputs FLOAT32.

// ---------------- kernel A: knn + build x0 (64ch x 64pts, f32) --------------
__global__ __launch_bounds__(64) void k_knn(const float* __restrict__ xyz,
    const float* __restrict__ feats, int* __restrict__ idxo, float* __restrict__ x0){
  int bm = blockIdx.x; int n = threadIdx.x;
  __shared__ float sx0[64], sx1[64], sx2[64], sxx[64];
  __shared__ float pd[64][65];
  const float* xp = xyz + (size_t)(bm*64+n)*3;
  float px=xp[0], py=xp[1], pz=xp[2];
  sx0[n]=px; sx1[n]=py; sx2[n]=pz; sxx[n]=px*px+py*py+pz*pz;
  __syncthreads();
  float xxn = sxx[n];
  for(int m=0;m<64;m++){
    float inner = px*sx0[m]+py*sx1[m]+pz*sx2[m];
    pd[n][m] = 2.0f*inner - xxn - sxx[m];
  }
  int* ip = idxo + bm*1024 + n*16;
  for(int j=0;j<16;j++){
    float best=-3.4e38f; int bi=0;
    for(int m=0;m<64;m++){ float v=pd[n][m]; if(v>best){best=v;bi=m;} }
    ip[j]=bi; pd[n][bi]=-3.4e38f;  // strict > keeps lowest index on ties (lax.top_k)
  }
  float* xb = x0 + (size_t)bm*4096;
  xb[0*64+n]=px; xb[1*64+n]=py; xb[2*64+n]=pz;
  const float* fp = feats + (size_t)(bm*64+n)*61;
  for(int c=0;c<61;c++) xb[(3+c)*64+n]=fp[c];
}

// ---------------- edgeconv (W loads are wave-uniform -> s_load) -------------
template<int O>
__global__ __launch_bounds__(256) void k_edge(const float* __restrict__ xin_g, int ld_in,
   const int* __restrict__ idxg, const float* __restrict__ W, const float* __restrict__ gg,
   const float* __restrict__ bb, float* __restrict__ outg, int ld_out){
  __shared__ float xin[4096];
  __shared__ float zs[4096];
  __shared__ float dds[4096];
  int bm=blockIdx.x, tid=threadIdx.x;
  for(int i=tid;i<4096;i+=256) xin[i]=xin_g[(size_t)bm*ld_in+i];
  const int* ip0 = idxg + bm*1024;
  for(int oc=0; oc<O; oc+=64){
    __syncthreads();
    for(int i=tid;i<4096;i+=256){
      int o=oc+(i>>6), m=i&63;   // i>>6 wave-uniform -> W reads go scalar path
      float az=0.f, ad=0.f;
      #pragma unroll 8
      for(int c=0;c<64;c++){
        float w1v=W[o*128+c];
        float w2v=W[o*128+64+c];
        float xv=xin[c*64+m];
        az += w1v*xv; ad += (w2v-w1v)*xv;
      }
      zs[i]=az; dds[i]=ad;
    }
    __syncthreads();
    for(int i=tid;i<4096;i+=256){
      int o=oc+(i>>6), n=i&63;
      float s=gg[o]*BNS, bi=bb[o];
      float base=dds[i];
      const int* ip=ip0+n*16;
      int zrow=(i>>6)<<6;
      float v=0.f;  // relu(max) == max(0, max_k pre-relu)
      #pragma unroll
      for(int k=0;k<16;k++){ int mi=ip[k]; v=fmaxf(v, s*(zs[zrow+mi]+base)+bi); }
      outg[(size_t)bm*ld_out + o*64+n]=v;
    }
  }
}

// ---------------- transpose W[O][K] -> Wt[K][O] (32x32 LDS tiles) -----------
__global__ __launch_bounds__(256) void k_tr(const float* __restrict__ in,
    float* __restrict__ out, int O, int K){
  __shared__ float s[32][33];
  int nt = O>>5;
  int to = blockIdx.x % nt, tk = blockIdx.x / nt;
  int c = threadIdx.x&31, r8 = threadIdx.x>>5;
  #pragma unroll
  for(int p=0;p<4;p++){
    int r = r8 + p*8;
    s[r][c] = in[(size_t)(to*32+r)*K + tk*32 + c];
  }
  __syncthreads();
  #pragma unroll
  for(int p=0;p<4;p++){
    int r = r8 + p*8;
    out[(size_t)(tk*32+r)*O + to*32 + c] = s[c][r];
  }
}

// ---------------- tiled GEMM: Y = Wt^T @ X per bm-group ---------------------
// Wt: [K][O] (pre-transposed). X: per bm [K][64], stride K*64.
// Tile: BM=32*TM outputs x 64 cols (one bm), BK=32. 256 thr, thread = TM x 8.
// EPI 0: out[bm*O*64+o*64+n] = relu(acc*s+b)
// EPI 1: out[...] *= sigmoid(acc + bias[o])   (gate, RMW)
// EPI 2: pool[(b*512+o)*256+m] = max(0, max_n(acc*s+b))
template<int TM, int EPI>
__global__ __launch_bounds__(256) void k_gemm(const float* __restrict__ Wt,
    const float* __restrict__ Xg, float* __restrict__ Og,
    const float* __restrict__ sg, const float* __restrict__ bg,
    int O, int K, int not_){
  constexpr int BM = 32*TM;
  __shared__ float As[32][BM];
  __shared__ float Bs[32][64];
  int blk = blockIdx.x;
  int ot = blk % not_;
  int bm = blk / not_;
  int o0 = ot*BM;
  int tid = threadIdx.x;
  int tx = tid&7, ty = tid>>3;
  float acc[TM][8];
  #pragma unroll
  for(int a=0;a<TM;a++)
    #pragma unroll
    for(int d=0;d<8;d++) acc[a][d]=0.f;
  const float* Xb = Xg + (size_t)bm*K*64;
  for(int k0=0;k0<K;k0+=32){
    __syncthreads();
    // A tile 32 x BM (coalesced float4 along o)
    constexpr int TPR = BM/4;
    constexpr int RPP = 256/TPR;
    #pragma unroll
    for(int p=0;p<32/RPP;p++){
      int r = p*RPP + tid/TPR;
      int c4 = (tid%TPR)*4;
      *(float4*)&As[r][c4] = *(const float4*)&Wt[(size_t)(k0+r)*O + o0 + c4];
    }
    // B tile 32 x 64
    #pragma unroll
    for(int p=0;p<2;p++){
      int r = p*16 + (tid>>4);
      int j = (tid&15)*4;
      *(float4*)&Bs[r][j] = *(const float4*)&Xb[(size_t)(k0+r)*64 + j];
    }
    __syncthreads();
    #pragma unroll
    for(int k=0;k<32;k++){
      float av[TM], bv[8];
      #pragma unroll
      for(int a=0;a<TM;a++) av[a]=As[k][ty*TM+a];
      #pragma unroll
      for(int d=0;d<8;d++) bv[d]=Bs[k][tx*8+d];
      #pragma unroll
      for(int a=0;a<TM;a++)
        #pragma unroll
        for(int d=0;d<8;d++) acc[a][d] += av[a]*bv[d];
    }
  }
  if(EPI==0){
    float* ob = Og + (size_t)bm*O*64;
    #pragma unroll
    for(int a=0;a<TM;a++){
      int o=o0+ty*TM+a;
      float s=sg[o]*BNS, bi=bg[o];
      float v[8];
      #pragma unroll
      for(int d=0;d<8;d++) v[d]=fmaxf(acc[a][d]*s+bi,0.f);
      float* p=&ob[o*64+tx*8];
      *(float4*)p     = make_float4(v[0],v[1],v[2],v[3]);
      *(float4*)(p+4) = make_float4(v[4],v[5],v[6],v[7]);
    }
  } else if(EPI==1){
    float* ob = Og + (size_t)bm*O*64;
    #pragma unroll
    for(int a=0;a<TM;a++){
      int o=o0+ty*TM+a;
      float bi=sg[o];
      float* p=&ob[o*64+tx*8];
      float4 u0=*(float4*)p, u1=*(float4*)(p+4);
      u0.x*=1.f/(1.f+__expf(-(acc[a][0]+bi)));
      u0.y*=1.f/(1.f+__expf(-(acc[a][1]+bi)));
      u0.z*=1.f/(1.f+__expf(-(acc[a][2]+bi)));
      u0.w*=1.f/(1.f+__expf(-(acc[a][3]+bi)));
      u1.x*=1.f/(1.f+__expf(-(acc[a][4]+bi)));
      u1.y*=1.f/(1.f+__expf(-(acc[a][5]+bi)));
      u1.z*=1.f/(1.f+__expf(-(acc[a][6]+bi)));
      u1.w*=1.f/(1.f+__expf(-(acc[a][7]+bi)));
      *(float4*)p=u0; *(float4*)(p+4)=u1;
    }
  } else {
    int b = bm>>8, m = bm&255;
    #pragma unroll
    for(int a=0;a<TM;a++){
      int o=o0+ty*TM+a;
      float s=sg[o]*BNS, bi=bg[o];
      float v=0.f;  // relu folded into max
      #pragma unroll
      for(int d=0;d<8;d++) v=fmaxf(v, acc[a][d]*s+bi);
      v=fmaxf(v,__shfl_xor(v,1));
      v=fmaxf(v,__shfl_xor(v,2));
      v=fmaxf(v,__shfl_xor(v,4));
      if(tx==0) Og[((size_t)b*512+o)*256+m]=v;
    }
  }
}

// ---------------- red: 512->256 bn relu, then bn(x+x,g1,b1) -----------------
__global__ __launch_bounds__(256) void k_red(const float* __restrict__ pool,
   const float* __restrict__ W, const float* __restrict__ g, const float* __restrict__ b,
   const float* __restrict__ g1, const float* __restrict__ b1, float* __restrict__ x1){
  int e=blockIdx.x*256+threadIdx.x;
  int bb=e>>16, o=(e>>8)&255, m=e&255;
  const float* pp=pool+(size_t)bb*131072+m;
  const float* wr=W+o*512;
  float acc=0.f;
  #pragma unroll 4
  for(int c=0;c<512;c++) acc+=wr[c]*pp[(size_t)c*256];
  float r=fmaxf(acc*g[o]*BNS+b[o],0.f);
  x1[e]=2.f*r*(g1[o]*BNS)+b1[o];
}

// ---------------- sc1: h = relu(W@x1 + b) -----------------------------------
__global__ __launch_bounds__(256) void k_sc1(const float* __restrict__ x1,
   const float* __restrict__ W, const float* __restrict__ b, float* __restrict__ h){
  int e=blockIdx.x*256+threadIdx.x;
  int bb=e>>16, o=(e>>8)&255, m=e&255;
  const float* xp=x1+(size_t)bb*65536+m;
  const float* wr=W+o*256;
  float acc=0.f;
  #pragma unroll 4
  for(int c=0;c<256;c++) acc+=wr[c]*xp[(size_t)c*256];
  h[e]=fmaxf(acc+b[o],0.f);
}

// ---------------- sc2 + residual + bn2 -> f32 out ---------------------------
__global__ __launch_bounds__(256) void k_sc2(const float* __restrict__ h,
   const float* __restrict__ x1, const float* __restrict__ W, const float* __restrict__ b,
   const float* __restrict__ g2, const float* __restrict__ b2, float* __restrict__ out){
  int e=blockIdx.x*256+threadIdx.x;
  int bb=e>>16, o=(e>>8)&255, m=e&255;
  const float* hp=h+(size_t)bb*65536+m;
  const float* wr=W+o*256;
  float acc=0.f;
  #pragma unroll 4
  for(int c=0;c<256;c++) acc+=wr[c]*hp[(size_t)c*256];
  float v=x1[e]+acc+b[o];
  out[e]=v*(g2[o]*BNS)+b2[o];
}

extern "C" void kernel_launch(void* const* d_in, const int* in_sizes, int n_in,
                              void* d_out, int out_size, void* d_ws, size_t ws_size,
                              hipStream_t stream){
  const float* xyz     =(const float*)d_in[0];
  const float* feats   =(const float*)d_in[1];
  const float* e1_w    =(const float*)d_in[2];
  const float* e1_g    =(const float*)d_in[3];
  const float* e1_b    =(const float*)d_in[4];
  const float* e2_w    =(const float*)d_in[5];
  const float* e2_g    =(const float*)d_in[6];
  const float* e2_b    =(const float*)d_in[7];
  const float* cal1_w  =(const float*)d_in[8];
  const float* cal1_g  =(const float*)d_in[9];
  const float* cal1_b  =(const float*)d_in[10];
  const float* cal2_w  =(const float*)d_in[11];
  const float* cal2_bias=(const float*)d_in[12];
  const float* exp1_w  =(const float*)d_in[13];
  const float* exp1_g  =(const float*)d_in[14];
  const float* exp1_b  =(const float*)d_in[15];
  const float* exp2_w  =(const float*)d_in[16];
  const float* exp2_g  =(const float*)d_in[17];
  const float* exp2_b  =(const float*)d_in[18];
  const float* red_w   =(const float*)d_in[19];
  const float* red_g   =(const float*)d_in[20];
  const float* red_b   =(const float*)d_in[21];
  const float* sc1_w   =(const float*)d_in[22];
  const float* sc1_b   =(const float*)d_in[23];
  const float* sc2_w   =(const float*)d_in[24];
  const float* sc2_b   =(const float*)d_in[25];
  const float* sc_n1_g =(const float*)d_in[26];
  const float* sc_n1_b =(const float*)d_in[27];
  const float* sc_n2_g =(const float*)d_in[28];
  const float* sc_n2_b =(const float*)d_in[29];

  char* wsb=(char*)d_ws;
  // workspace layout (bytes):
  int*   idx =(int*)  (wsb + 0);          // 2 MB; dead after edge2 -> reused for Wt
  float* x0  =(float*)(wsb + 2097152);    // 8 MB (reused as c1)
  float* cat =(float*)(wsb + 10485760);   // 24 MB
  float* p1  =(float*)(wsb + 35651584);   // 32 MB
  float* pool=(float*)(wsb + 69206016);   // 1 MB
  float* x1  =(float*)(wsb + 70254592);
  float* hbuf=(float*)(wsb + 70778880);
  float* c1  = x0;                        // x0 dead after edge2
  // transposed weights overlay the idx region (idx dead after edge2):
  float* Wt_c1=(float*)(wsb + 0);         // 192x64   = 48 KB
  float* Wt_c2=(float*)(wsb + 49152);     // 64x192   = 48 KB
  float* Wt_e1=(float*)(wsb + 98304);     // 192x256  = 192 KB
  float* Wt_e2=(float*)(wsb + 294912);    // 256x512  = 512 KB

  k_knn      <<<512, 64,0,stream>>>(xyz,feats,idx,x0);
  k_edge< 64><<<512,256,0,stream>>>(x0,   4096,idx,e1_w,e1_g,e1_b,cat,     12288);
  k_edge<128><<<512,256,0,stream>>>(cat, 12288,idx,e2_w,e2_g,e2_b,cat+4096,12288);
  // pre-transpose the tid-indexed weight matrices (idx now dead)
  k_tr       <<< 12,256,0,stream>>>(cal1_w,Wt_c1, 64,192);
  k_tr       <<< 12,256,0,stream>>>(cal2_w,Wt_c2,192, 64);
  k_tr       <<< 48,256,0,stream>>>(exp1_w,Wt_e1,256,192);
  k_tr       <<<128,256,0,stream>>>(exp2_w,Wt_e2,512,256);
  // cal1: 192->64 bn+relu
  k_gemm<2,0><<<512*1,256,0,stream>>>(Wt_c1,cat,c1,  cal1_g,cal1_b, 64,192,1);
  // cal2: 64->192 + bias, sigmoid gate onto cat (RMW)
  k_gemm<2,1><<<512*3,256,0,stream>>>(Wt_c2,c1, cat, cal2_bias,cal2_bias,192,64,3);
  // exp1: 192->256 bn+relu
  k_gemm<4,0><<<512*2,256,0,stream>>>(Wt_e1,cat,p1,  exp1_g,exp1_b,256,192,2);
  // exp2: 256->512 bn+relu + maxpool over n -> pool(b,512,m)
  k_gemm<4,2><<<512*4,256,0,stream>>>(Wt_e2,p1, pool,exp2_g,exp2_b,512,256,4);
  k_red      <<<512,256,0,stream>>>(pool,red_w,red_g,red_b,sc_n1_g,sc_n1_b,x1);
  k_sc1      <<<512,256,0,stream>>>(x1,sc1_w,sc1_b,hbuf);
  k_sc2      <<<512,256,0,stream>>>(hbuf,x1,sc2_w,sc2_b,sc_n2_g,sc_n2_b,(float*)d_out);
}